// Round 1
// baseline (248.599 us; speedup 1.0000x reference)
//
#include <hip/hip_runtime.h>

// SAGEConv — fp8-gather + fused aggregate/GEMM version.
// R6 post-mortem: k_agg neutral at 66us despite 2x grid & 4 chains ->
// limiter is random-gather delivery (410MB of 256B rows, ~6.2TB/s eff),
// not latency hiding. R7: (a) gather from an fp8-e4m3 copy of h (128B/row,
// half the lines); (b) fuse GEMM into the bucket kernel (means land in a
// padded LDS A-tile, B streamed from L2-resident Wp, out written direct) —
// deletes k_gemm + 51MB nb round-trip; (c) bhist folded into cvt_h,
// bscan+cvt_w merged. 5 dispatches total.
// R8: identical re-submit — prior bench was an infra failure (container
// died twice, no counters). Need the baseline profile before editing.

constexpr int NN = 100000;
constexpr int NE = 1600000;
constexpr int D  = 128;
constexpr int BK = 64;                      // nodes per bucket
constexpr int NB = (NN + BK - 1) / BK;      // 1563 buckets
constexpr int PB = 8192;                    // edges per partition block
constexpr int CAPB = 2048;                  // max edges/bucket (mean 1024, sigma 32)
constexpr int XST = 264;                    // Xs row stride (shorts): 264*2B=528B -> bank stride 4

typedef __attribute__((ext_vector_type(8))) short short8;   // 8 bf16 (4 VGPR)
typedef __attribute__((ext_vector_type(4))) float floatx4;  // MFMA C/D
typedef __attribute__((ext_vector_type(2))) float floatx2;

static __device__ __forceinline__ unsigned short f2bf(float f) {
    unsigned u = __float_as_uint(f);
    unsigned r = ((u >> 16) & 1u) + 0x7fffu;
    return (unsigned short)((u + r) >> 16);
}

// ---------------------------------------------------------------------------
// h (fp32) -> hb (bf16) + hf8 (e4m3). First 128 blocks also build the
// dst-bucket histogram (grid-stride) — fused k_bhist.
// ---------------------------------------------------------------------------
__global__ __launch_bounds__(256) void k_cvt_h(
    const float* __restrict__ h, const int* __restrict__ dst,
    unsigned short* __restrict__ hb, uint2* __restrict__ hf8,
    int* __restrict__ bcnt)
{
    __shared__ int lh[NB];
    int i = blockIdx.x * 256 + threadIdx.x;          // NN*D/8 = 1.6M, exact
    const float4* h4 = (const float4*)h;
    float4 a = h4[(size_t)i * 2];
    float4 b = h4[(size_t)i * 2 + 1];
    uint4 o;
    o.x = (unsigned)f2bf(a.x) | ((unsigned)f2bf(a.y) << 16);
    o.y = (unsigned)f2bf(a.z) | ((unsigned)f2bf(a.w) << 16);
    o.z = (unsigned)f2bf(b.x) | ((unsigned)f2bf(b.y) << 16);
    o.w = (unsigned)f2bf(b.z) | ((unsigned)f2bf(b.w) << 16);
    ((uint4*)hb)[i] = o;
    unsigned q0 = __builtin_amdgcn_cvt_pk_fp8_f32(a.x, a.y, 0u, false);
    q0          = __builtin_amdgcn_cvt_pk_fp8_f32(a.z, a.w, q0, true);
    unsigned q1 = __builtin_amdgcn_cvt_pk_fp8_f32(b.x, b.y, 0u, false);
    q1          = __builtin_amdgcn_cvt_pk_fp8_f32(b.z, b.w, q1, true);
    hf8[i] = make_uint2(q0, q1);

    if (blockIdx.x < 128) {                          // fused bucket histogram
        for (int k = threadIdx.x; k < NB; k += 256) lh[k] = 0;
        __syncthreads();
        for (int e = blockIdx.x * 256 + threadIdx.x; e < NE; e += 128 * 256)
            atomicAdd(&lh[dst[e] >> 6], 1);
        __syncthreads();
        for (int k = threadIdx.x; k < NB; k += 256)
            if (lh[k]) atomicAdd(&bcnt[k], lh[k]);
    }
}

// ---------------------------------------------------------------------------
// Block 0: exclusive scan of bucket counts -> bbase/bcursor.
// Blocks 1..16: pack Wcat into B-fragment order (bf16), 2 kg per block.
// ---------------------------------------------------------------------------
__global__ __launch_bounds__(256) void k_scan_cvtw(
    const int* __restrict__ bcnt, int* __restrict__ bbase,
    int* __restrict__ bcursor, const float* __restrict__ Wself,
    const float* __restrict__ Wneigh, unsigned short* __restrict__ Wp)
{
    const int t = threadIdx.x;
    if (blockIdx.x == 0) {
        __shared__ int sd[256];
        const int base = t * 7;
        int c[7];
        int local = 0;
#pragma unroll
        for (int j = 0; j < 7; ++j) {
            int idx = base + j;
            c[j] = (idx < NB) ? bcnt[idx] : 0;
            local += c[j];
        }
        sd[t] = local;
        __syncthreads();
        for (int off = 1; off < 256; off <<= 1) {
            int v = (t >= off) ? sd[t - off] : 0;
            __syncthreads();
            sd[t] += v;
            __syncthreads();
        }
        int run = sd[t] - local;
#pragma unroll
        for (int j = 0; j < 7; ++j) {
            int idx = base + j;
            if (idx < NB) { bbase[idx] = run; bcursor[idx] = run; }
            run += c[j];
        }
        if (t == 255) bbase[NB] = run;   // == NE
    } else {
        int kg  = (blockIdx.x - 1) * 2 + (t >> 7);   // 0..31
        int col = t & 127;
        unsigned short v[8];
#pragma unroll
        for (int j = 0; j < 8; ++j) {
            int k = kg * 8 + j;
            const float* W = (k < 128) ? (Wself + (size_t)k * D)
                                       : (Wneigh + (size_t)(k - 128) * D);
            v[j] = f2bf(W[col]);
        }
        uint4 o;
        o.x = (unsigned)v[0] | ((unsigned)v[1] << 16);
        o.y = (unsigned)v[2] | ((unsigned)v[3] << 16);
        o.z = (unsigned)v[4] | ((unsigned)v[5] << 16);
        o.w = (unsigned)v[6] | ((unsigned)v[7] << 16);
        ((uint4*)Wp)[kg * 128 + col] = o;
    }
}

// ---------------------------------------------------------------------------
// Partition edges into bucket-contiguous packed[] = src | (dst&63)<<17.
// LDS-rank within block; one global reserve atomic per (block, bucket).
// ---------------------------------------------------------------------------
__global__ __launch_bounds__(256) void k_part(
    const int* __restrict__ src, const int* __restrict__ dst,
    int* __restrict__ bcursor, unsigned* __restrict__ packed)
{
    __shared__ int lh[NB];
    const int t = threadIdx.x;
    const int e0 = blockIdx.x * PB;

    for (int i = t; i < NB; i += 256) lh[i] = 0;
    __syncthreads();

    int myd[32];
#pragma unroll
    for (int j = 0; j < 32; ++j) {
        int e = e0 + j * 256 + t;
        myd[j] = (e < NE) ? dst[e] : -1;
        if (myd[j] >= 0) atomicAdd(&lh[myd[j] >> 6], 1);
    }
    __syncthreads();
    for (int i = t; i < NB; i += 256) {
        int c = lh[i];
        if (c) lh[i] = atomicAdd(&bcursor[i], c);
    }
    __syncthreads();
#pragma unroll
    for (int j = 0; j < 32; ++j) {
        int e = e0 + j * 256 + t;
        if (myd[j] >= 0) {
            int b = myd[j] >> 6;
            int pos = atomicAdd(&lh[b], 1);
            packed[pos] = (unsigned)src[e] | ((unsigned)(myd[j] & 63) << 17);
        }
    }
}

// ---------------------------------------------------------------------------
// Fused per-bucket kernel: counting-sort src (LDS), fp8 gather + fp32
// register accumulation (4 chains), write mean bf16 into padded LDS A-tile
// Xs[64][264] alongside preloaded self-rows, then MFMA
// out[64x128] = Xs @ Wcat with B-frags streamed from L2-resident Wp.
// LDS ~42KB -> 3 blocks/CU.
// ---------------------------------------------------------------------------
__global__ __launch_bounds__(256) void k_agg_gemm(
    const unsigned short* __restrict__ hb, const uint2* __restrict__ hf8,
    const int* __restrict__ bbase, const unsigned* __restrict__ packed,
    const unsigned short* __restrict__ Wp, float* __restrict__ out)
{
    __shared__ unsigned short Xs[BK][XST];     // 33.7 KiB A-tile (bf16)
    __shared__ unsigned sorted[CAPB];          // 8 KiB
    __shared__ int cnt[BK], offs[BK], cur[BK];

    const int t      = threadIdx.x;
    const int bucket = blockIdx.x;
    const int ebeg   = bbase[bucket];
    const int ecnt   = min(bbase[bucket + 1] - ebeg, CAPB);

    // ---- Phase 0: preload own-node h rows (bf16) into Xs cols 0..127 ----
    const uint4* __restrict__ hb4 = (const uint4*)hb;
#pragma unroll
    for (int i = 0; i < 4; ++i) {
        int u   = t + i * 256;          // 0..1023
        int row = u >> 4, c = u & 15;
        int g   = bucket * BK + row;
        uint4 val = hb4[(size_t)min(g, NN - 1) * 16 + c];
        *(uint4*)&Xs[row][c * 8] = val;
    }
    if (t < BK) cnt[t] = 0;
    __syncthreads();

    // ---- Phase A: counting sort of the bucket's edges into LDS ----
    unsigned pk[8];
#pragma unroll
    for (int i = 0; i < 8; ++i) {
        int idx = t + i * 256;
        pk[i] = (idx < ecnt) ? packed[ebeg + idx] : 0u;
        if (idx < ecnt) atomicAdd(&cnt[(pk[i] >> 17) & 63u], 1);
    }
    __syncthreads();
    if (t < BK) {                       // 64-wide shuffle scan (wave 0)
        int v = cnt[t];
        int sum = v;
#pragma unroll
        for (int off = 1; off < 64; off <<= 1) {
            int u = __shfl_up(sum, off, 64);
            if (t >= off) sum += u;
        }
        offs[t] = sum - v;
        cur[t]  = sum - v;
    }
    __syncthreads();
#pragma unroll
    for (int i = 0; i < 8; ++i) {
        int idx = t + i * 256;
        if (idx < ecnt) {
            int pos = atomicAdd(&cur[(pk[i] >> 17) & 63u], 1);
            sorted[pos] = pk[i] & 0x1FFFFu;
        }
    }
    __syncthreads();

    // ---- Phase B: fp8 gather, fp32 accumulate, mean -> Xs cols 128..255 ----
    const int slot = t >> 4;            // 0..15
    const int l16  = t & 15;
#pragma unroll
    for (int ni = 0; ni < 4; ++ni) {
        int node = slot + ni * 16;      // 0..63
        const int beg = offs[node];
        const int n   = cnt[node];
        float a0[8] = {0,0,0,0,0,0,0,0};
        float a1[8] = {0,0,0,0,0,0,0,0};
        float a2[8] = {0,0,0,0,0,0,0,0};
        float a3[8] = {0,0,0,0,0,0,0,0};
        int e = 0;
        for (; e + 3 < n; e += 4) {
            uint2 x0 = hf8[(size_t)sorted[beg + e]     * 16 + l16];
            uint2 x1 = hf8[(size_t)sorted[beg + e + 1] * 16 + l16];
            uint2 x2 = hf8[(size_t)sorted[beg + e + 2] * 16 + l16];
            uint2 x3 = hf8[(size_t)sorted[beg + e + 3] * 16 + l16];
#pragma unroll
            for (int half = 0; half < 2; ++half) {
                unsigned w0 = half ? x0.y : x0.x, w1 = half ? x1.y : x1.x;
                unsigned w2 = half ? x2.y : x2.x, w3 = half ? x3.y : x3.x;
                floatx2 p;
                p = __builtin_amdgcn_cvt_pk_f32_fp8(w0, false); a0[half*4+0]+=p.x; a0[half*4+1]+=p.y;
                p = __builtin_amdgcn_cvt_pk_f32_fp8(w0, true);  a0[half*4+2]+=p.x; a0[half*4+3]+=p.y;
                p = __builtin_amdgcn_cvt_pk_f32_fp8(w1, false); a1[half*4+0]+=p.x; a1[half*4+1]+=p.y;
                p = __builtin_amdgcn_cvt_pk_f32_fp8(w1, true);  a1[half*4+2]+=p.x; a1[half*4+3]+=p.y;
                p = __builtin_amdgcn_cvt_pk_f32_fp8(w2, false); a2[half*4+0]+=p.x; a2[half*4+1]+=p.y;
                p = __builtin_amdgcn_cvt_pk_f32_fp8(w2, true);  a2[half*4+2]+=p.x; a2[half*4+3]+=p.y;
                p = __builtin_amdgcn_cvt_pk_f32_fp8(w3, false); a3[half*4+0]+=p.x; a3[half*4+1]+=p.y;
                p = __builtin_amdgcn_cvt_pk_f32_fp8(w3, true);  a3[half*4+2]+=p.x; a3[half*4+3]+=p.y;
            }
        }
        for (; e < n; ++e) {
            uint2 x = hf8[(size_t)sorted[beg + e] * 16 + l16];
#pragma unroll
            for (int half = 0; half < 2; ++half) {
                unsigned w = half ? x.y : x.x;
                floatx2 p;
                p = __builtin_amdgcn_cvt_pk_f32_fp8(w, false); a0[half*4+0]+=p.x; a0[half*4+1]+=p.y;
                p = __builtin_amdgcn_cvt_pk_f32_fp8(w, true);  a0[half*4+2]+=p.x; a0[half*4+3]+=p.y;
            }
        }
        float inv = (n > 0) ? 1.0f / (float)n : 0.0f;
        unsigned short m[8];
#pragma unroll
        for (int j = 0; j < 8; ++j)
            m[j] = f2bf((a0[j] + a1[j] + a2[j] + a3[j]) * inv);
        uint4 o;
        o.x = (unsigned)m[0] | ((unsigned)m[1] << 16);
        o.y = (unsigned)m[2] | ((unsigned)m[3] << 16);
        o.z = (unsigned)m[4] | ((unsigned)m[5] << 16);
        o.w = (unsigned)m[6] | ((unsigned)m[7] << 16);
        *(uint4*)&Xs[node][128 + l16 * 8] = o;
    }
    __syncthreads();

    // ---- Phase C: MFMA  out[64x128] = Xs(64x256) @ Wcat(256x128) ----
    const int wave = t >> 6;
    const int lane = t & 63;
    const int wl16 = lane & 15;
    const int kg4  = lane >> 4;          // 0..3
    floatx4 acc[8];
#pragma unroll
    for (int ct = 0; ct < 8; ++ct) acc[ct] = (floatx4){0.f, 0.f, 0.f, 0.f};

    const int arow = wave * 16 + wl16;   // 0..63
#pragma unroll
    for (int ks = 0; ks < 8; ++ks) {
        const short8 a = *(const short8*)&Xs[arow][ks * 32 + kg4 * 8];
#pragma unroll
        for (int ct = 0; ct < 8; ++ct) {
            const short8 b = *(const short8*)(Wp + (((ks * 4 + kg4) * 128) + ct * 16 + wl16) * 8);
            acc[ct] = __builtin_amdgcn_mfma_f32_16x16x32_bf16(a, b, acc[ct], 0, 0, 0);
        }
    }

    // C/D layout: col = lane&15, row = (lane>>4)*4 + reg
    const int rbase = bucket * BK + wave * 16 + kg4 * 4;
#pragma unroll
    for (int r = 0; r < 4; ++r) {
        int row = rbase + r;
        if (row < NN) {
            float* o = out + (size_t)row * D + wl16;
#pragma unroll
            for (int ct = 0; ct < 8; ++ct)
                o[ct * 16] = acc[ct][r];
        }
    }
}

extern "C" void kernel_launch(void* const* d_in, const int* in_sizes, int n_in,
                              void* d_out, int out_size, void* d_ws, size_t ws_size,
                              hipStream_t stream) {
    const float* h      = (const float*)d_in[0];
    const int*   src    = (const int*)d_in[1];
    const int*   dst    = (const int*)d_in[2];
    const float* Wself  = (const float*)d_in[3];
    const float* Wneigh = (const float*)d_in[4];
    float*       out    = (float*)d_out;

    // workspace layout (~45 MB)
    unsigned short* hb = (unsigned short*)d_ws;            // NN*D bf16 (25.6MB)
    uint2* hf8         = (uint2*)(hb + (size_t)NN * D);    // NN*D/8 uint2 (12.8MB)
    unsigned short* Wp = (unsigned short*)(hf8 + (size_t)NN * D / 8);  // 64KB
    unsigned* packed   = (unsigned*)(Wp + 256 * D);        // NE (6.4MB)
    int* bcnt          = (int*)(packed + NE);              // NB
    int* bbase         = bcnt + NB;                        // NB+1
    int* bcursor       = bbase + NB + 1;                   // NB

    hipMemsetAsync(bcnt, 0, NB * sizeof(int), stream);

    k_cvt_h    <<<dim3(NN * D / 8 / 256), 256, 0, stream>>>(h, dst, hb, hf8, bcnt);
    k_scan_cvtw<<<dim3(17), 256, 0, stream>>>(bcnt, bbase, bcursor, Wself, Wneigh, Wp);
    k_part     <<<dim3((NE + PB - 1) / PB), 256, 0, stream>>>(src, dst, bcursor, packed);
    k_agg_gemm <<<dim3(NB), 256, 0, stream>>>(hb, hf8, bbase, packed, Wp, out);
}

// Round 2
// 237.438 us; speedup vs baseline: 1.0470x; 1.0470x over previous
//
#include <hip/hip_runtime.h>

// SAGEConv — fp8-gather + fused aggregate/GEMM.
// R8 baseline profile: total 248.6us; k_agg_gemm 76us with MfmaUtil 3.2%,
// VALUBusy 26%, HBM 24%, Occ 22.6% -> latency-chain bound, nothing saturated.
// Other ~170us hidden below top-5 cut: theory = global-atomic hotspotting on
// dense 6KB bcnt/bcursor (~470K atomicAdds onto ~49 lines -> channel
// serialization in k_cvt_h-hist + k_part).
// R9: (a) pad bcnt/bcursor to 128B/bucket (one line per counter);
//     (b) k_agg_gemm 512 threads: 32 gather groups x 2 nodes, 8-deep load
//         unroll -> chain steps/wave ~24 -> ~6, 8 loads in flight/group;
//         Phase C split over 8 waves (4 accs each);
//     (c) histogram over 256 blocks (shorter serial tail).

constexpr int NN = 100000;
constexpr int NE = 1600000;
constexpr int D  = 128;
constexpr int BK = 64;                      // nodes per bucket
constexpr int NB = (NN + BK - 1) / BK;      // 1563 buckets
constexpr int PB = 8192;                    // edges per partition block
constexpr int CAPB = 2048;                  // max edges/bucket (mean 1024, sigma 32)
constexpr int XST = 264;                    // Xs row stride (shorts): 528B -> bank stride 4
constexpr int PADI = 32;                    // ints per bucket counter slot (128B line)

typedef __attribute__((ext_vector_type(8))) short short8;   // 8 bf16 (4 VGPR)
typedef __attribute__((ext_vector_type(4))) float floatx4;  // MFMA C/D
typedef __attribute__((ext_vector_type(2))) float floatx2;

static __device__ __forceinline__ unsigned short f2bf(float f) {
    unsigned u = __float_as_uint(f);
    unsigned r = ((u >> 16) & 1u) + 0x7fffu;
    return (unsigned short)((u + r) >> 16);
}

// ---------------------------------------------------------------------------
// h (fp32) -> hb (bf16) + hf8 (e4m3). First 256 blocks also build the
// dst-bucket histogram (grid-stride) into PADDED bcnt.
// ---------------------------------------------------------------------------
__global__ __launch_bounds__(256) void k_cvt_h(
    const float* __restrict__ h, const int* __restrict__ dst,
    unsigned short* __restrict__ hb, uint2* __restrict__ hf8,
    int* __restrict__ bcnt)
{
    __shared__ int lh[NB];
    int i = blockIdx.x * 256 + threadIdx.x;          // NN*D/8 = 1.6M, exact
    const float4* h4 = (const float4*)h;
    float4 a = h4[(size_t)i * 2];
    float4 b = h4[(size_t)i * 2 + 1];
    uint4 o;
    o.x = (unsigned)f2bf(a.x) | ((unsigned)f2bf(a.y) << 16);
    o.y = (unsigned)f2bf(a.z) | ((unsigned)f2bf(a.w) << 16);
    o.z = (unsigned)f2bf(b.x) | ((unsigned)f2bf(b.y) << 16);
    o.w = (unsigned)f2bf(b.z) | ((unsigned)f2bf(b.w) << 16);
    ((uint4*)hb)[i] = o;
    unsigned q0 = __builtin_amdgcn_cvt_pk_fp8_f32(a.x, a.y, 0u, false);
    q0          = __builtin_amdgcn_cvt_pk_fp8_f32(a.z, a.w, q0, true);
    unsigned q1 = __builtin_amdgcn_cvt_pk_fp8_f32(b.x, b.y, 0u, false);
    q1          = __builtin_amdgcn_cvt_pk_fp8_f32(b.z, b.w, q1, true);
    hf8[i] = make_uint2(q0, q1);

    if (blockIdx.x < 256) {                          // fused bucket histogram
        for (int k = threadIdx.x; k < NB; k += 256) lh[k] = 0;
        __syncthreads();
        for (int e = blockIdx.x * 256 + threadIdx.x; e < NE; e += 256 * 256)
            atomicAdd(&lh[dst[e] >> 6], 1);
        __syncthreads();
        for (int k = threadIdx.x; k < NB; k += 256)
            if (lh[k]) atomicAdd(&bcnt[(size_t)k * PADI], lh[k]);
    }
}

// ---------------------------------------------------------------------------
// Block 0: exclusive scan of padded bucket counts -> dense bbase + padded
// bcursor. Blocks 1..16: pack Wcat into B-fragment order (bf16).
// ---------------------------------------------------------------------------
__global__ __launch_bounds__(256) void k_scan_cvtw(
    const int* __restrict__ bcnt, int* __restrict__ bbase,
    int* __restrict__ bcursor, const float* __restrict__ Wself,
    const float* __restrict__ Wneigh, unsigned short* __restrict__ Wp)
{
    const int t = threadIdx.x;
    if (blockIdx.x == 0) {
        __shared__ int sd[256];
        const int base = t * 7;
        int c[7];
        int local = 0;
#pragma unroll
        for (int j = 0; j < 7; ++j) {
            int idx = base + j;
            c[j] = (idx < NB) ? bcnt[(size_t)idx * PADI] : 0;
            local += c[j];
        }
        sd[t] = local;
        __syncthreads();
        for (int off = 1; off < 256; off <<= 1) {
            int v = (t >= off) ? sd[t - off] : 0;
            __syncthreads();
            sd[t] += v;
            __syncthreads();
        }
        int run = sd[t] - local;
#pragma unroll
        for (int j = 0; j < 7; ++j) {
            int idx = base + j;
            if (idx < NB) { bbase[idx] = run; bcursor[(size_t)idx * PADI] = run; }
            run += c[j];
        }
        if (t == 255) bbase[NB] = run;   // == NE
    } else {
        int kg  = (blockIdx.x - 1) * 2 + (t >> 7);   // 0..31
        int col = t & 127;
        unsigned short v[8];
#pragma unroll
        for (int j = 0; j < 8; ++j) {
            int k = kg * 8 + j;
            const float* W = (k < 128) ? (Wself + (size_t)k * D)
                                       : (Wneigh + (size_t)(k - 128) * D);
            v[j] = f2bf(W[col]);
        }
        uint4 o;
        o.x = (unsigned)v[0] | ((unsigned)v[1] << 16);
        o.y = (unsigned)v[2] | ((unsigned)v[3] << 16);
        o.z = (unsigned)v[4] | ((unsigned)v[5] << 16);
        o.w = (unsigned)v[6] | ((unsigned)v[7] << 16);
        ((uint4*)Wp)[kg * 128 + col] = o;
    }
}

// ---------------------------------------------------------------------------
// Partition edges into bucket-contiguous packed[] = src | (dst&63)<<17.
// LDS-rank within block; one PADDED global reserve atomic per (block,bucket).
// ---------------------------------------------------------------------------
__global__ __launch_bounds__(256) void k_part(
    const int* __restrict__ src, const int* __restrict__ dst,
    int* __restrict__ bcursor, unsigned* __restrict__ packed)
{
    __shared__ int lh[NB];
    const int t = threadIdx.x;
    const int e0 = blockIdx.x * PB;

    for (int i = t; i < NB; i += 256) lh[i] = 0;
    __syncthreads();

    int myd[32];
#pragma unroll
    for (int j = 0; j < 32; ++j) {
        int e = e0 + j * 256 + t;
        myd[j] = (e < NE) ? dst[e] : -1;
        if (myd[j] >= 0) atomicAdd(&lh[myd[j] >> 6], 1);
    }
    __syncthreads();
    for (int i = t; i < NB; i += 256) {
        int c = lh[i];
        if (c) lh[i] = atomicAdd(&bcursor[(size_t)i * PADI], c);
    }
    __syncthreads();
#pragma unroll
    for (int j = 0; j < 32; ++j) {
        int e = e0 + j * 256 + t;
        if (myd[j] >= 0) {
            int b = myd[j] >> 6;
            int pos = atomicAdd(&lh[b], 1);
            packed[pos] = (unsigned)src[e] | ((unsigned)(myd[j] & 63) << 17);
        }
    }
}

// ---------------------------------------------------------------------------
// Fused per-bucket kernel, 512 threads: counting-sort src (LDS), fp8 gather
// with 8-deep chains (32 groups x 2 nodes), mean bf16 into padded LDS A-tile,
// then MFMA out[64x128] = Xs @ Wcat over 8 waves (4 col-tiles each).
// LDS ~42.5KB.
// ---------------------------------------------------------------------------
__global__ __launch_bounds__(512) void k_agg_gemm(
    const unsigned short* __restrict__ hb, const uint2* __restrict__ hf8,
    const int* __restrict__ bbase, const unsigned* __restrict__ packed,
    const unsigned short* __restrict__ Wp, float* __restrict__ out)
{
    __shared__ unsigned short Xs[BK][XST];     // 33.7 KiB A-tile (bf16)
    __shared__ unsigned sorted[CAPB];          // 8 KiB
    __shared__ int cnt[BK], offs[BK], cur[BK];

    const int t      = threadIdx.x;
    const int bucket = blockIdx.x;
    const int ebeg   = bbase[bucket];
    const int ecnt   = min(bbase[bucket + 1] - ebeg, CAPB);

    // ---- Phase 0: preload own-node h rows (bf16) into Xs cols 0..127 ----
    const uint4* __restrict__ hb4 = (const uint4*)hb;
#pragma unroll
    for (int i = 0; i < 2; ++i) {
        int u   = t + i * 512;          // 0..1023
        int row = u >> 4, c = u & 15;
        int g   = bucket * BK + row;
        uint4 val = hb4[(size_t)min(g, NN - 1) * 16 + c];
        *(uint4*)&Xs[row][c * 8] = val;
    }
    if (t < BK) cnt[t] = 0;
    __syncthreads();

    // ---- Phase A: counting sort of the bucket's edges into LDS ----
    unsigned pk[4];
#pragma unroll
    for (int i = 0; i < 4; ++i) {
        int idx = t + i * 512;
        pk[i] = (idx < ecnt) ? packed[ebeg + idx] : 0u;
        if (idx < ecnt) atomicAdd(&cnt[(pk[i] >> 17) & 63u], 1);
    }
    __syncthreads();
    if (t < BK) {                       // 64-wide shuffle scan (wave 0)
        int v = cnt[t];
        int sum = v;
#pragma unroll
        for (int off = 1; off < 64; off <<= 1) {
            int u = __shfl_up(sum, off, 64);
            if (t >= off) sum += u;
        }
        offs[t] = sum - v;
        cur[t]  = sum - v;
    }
    __syncthreads();
#pragma unroll
    for (int i = 0; i < 4; ++i) {
        int idx = t + i * 512;
        if (idx < ecnt) {
            int pos = atomicAdd(&cur[(pk[i] >> 17) & 63u], 1);
            sorted[pos] = pk[i] & 0x1FFFFu;
        }
    }
    __syncthreads();

    // ---- Phase B: fp8 gather, fp32 accumulate, mean -> Xs cols 128..255 ----
    // 32 groups of 16 lanes; each group: 2 nodes serially, 8 loads in flight.
    const int slot = t >> 4;            // 0..31
    const int l16  = t & 15;
#pragma unroll
    for (int ni = 0; ni < 2; ++ni) {
        int node = slot + ni * 32;      // 0..63
        const int beg = offs[node];
        const int n   = cnt[node];
        float a0[8] = {0,0,0,0,0,0,0,0};
        float a1[8] = {0,0,0,0,0,0,0,0};
        float a2[8] = {0,0,0,0,0,0,0,0};
        float a3[8] = {0,0,0,0,0,0,0,0};
        int e = 0;
        for (; e + 7 < n; e += 8) {
            uint2 x0 = hf8[(size_t)sorted[beg + e]     * 16 + l16];
            uint2 x1 = hf8[(size_t)sorted[beg + e + 1] * 16 + l16];
            uint2 x2 = hf8[(size_t)sorted[beg + e + 2] * 16 + l16];
            uint2 x3 = hf8[(size_t)sorted[beg + e + 3] * 16 + l16];
            uint2 x4 = hf8[(size_t)sorted[beg + e + 4] * 16 + l16];
            uint2 x5 = hf8[(size_t)sorted[beg + e + 5] * 16 + l16];
            uint2 x6 = hf8[(size_t)sorted[beg + e + 6] * 16 + l16];
            uint2 x7 = hf8[(size_t)sorted[beg + e + 7] * 16 + l16];
#pragma unroll
            for (int half = 0; half < 2; ++half) {
                unsigned w0 = half ? x0.y : x0.x, w1 = half ? x1.y : x1.x;
                unsigned w2 = half ? x2.y : x2.x, w3 = half ? x3.y : x3.x;
                unsigned w4 = half ? x4.y : x4.x, w5 = half ? x5.y : x5.x;
                unsigned w6 = half ? x6.y : x6.x, w7 = half ? x7.y : x7.x;
                floatx2 p;
                p = __builtin_amdgcn_cvt_pk_f32_fp8(w0, false); a0[half*4+0]+=p.x; a0[half*4+1]+=p.y;
                p = __builtin_amdgcn_cvt_pk_f32_fp8(w0, true);  a0[half*4+2]+=p.x; a0[half*4+3]+=p.y;
                p = __builtin_amdgcn_cvt_pk_f32_fp8(w1, false); a1[half*4+0]+=p.x; a1[half*4+1]+=p.y;
                p = __builtin_amdgcn_cvt_pk_f32_fp8(w1, true);  a1[half*4+2]+=p.x; a1[half*4+3]+=p.y;
                p = __builtin_amdgcn_cvt_pk_f32_fp8(w2, false); a2[half*4+0]+=p.x; a2[half*4+1]+=p.y;
                p = __builtin_amdgcn_cvt_pk_f32_fp8(w2, true);  a2[half*4+2]+=p.x; a2[half*4+3]+=p.y;
                p = __builtin_amdgcn_cvt_pk_f32_fp8(w3, false); a3[half*4+0]+=p.x; a3[half*4+1]+=p.y;
                p = __builtin_amdgcn_cvt_pk_f32_fp8(w3, true);  a3[half*4+2]+=p.x; a3[half*4+3]+=p.y;
                p = __builtin_amdgcn_cvt_pk_f32_fp8(w4, false); a0[half*4+0]+=p.x; a0[half*4+1]+=p.y;
                p = __builtin_amdgcn_cvt_pk_f32_fp8(w4, true);  a0[half*4+2]+=p.x; a0[half*4+3]+=p.y;
                p = __builtin_amdgcn_cvt_pk_f32_fp8(w5, false); a1[half*4+0]+=p.x; a1[half*4+1]+=p.y;
                p = __builtin_amdgcn_cvt_pk_f32_fp8(w5, true);  a1[half*4+2]+=p.x; a1[half*4+3]+=p.y;
                p = __builtin_amdgcn_cvt_pk_f32_fp8(w6, false); a2[half*4+0]+=p.x; a2[half*4+1]+=p.y;
                p = __builtin_amdgcn_cvt_pk_f32_fp8(w6, true);  a2[half*4+2]+=p.x; a2[half*4+3]+=p.y;
                p = __builtin_amdgcn_cvt_pk_f32_fp8(w7, false); a3[half*4+0]+=p.x; a3[half*4+1]+=p.y;
                p = __builtin_amdgcn_cvt_pk_f32_fp8(w7, true);  a3[half*4+2]+=p.x; a3[half*4+3]+=p.y;
            }
        }
        for (; e + 3 < n; e += 4) {
            uint2 x0 = hf8[(size_t)sorted[beg + e]     * 16 + l16];
            uint2 x1 = hf8[(size_t)sorted[beg + e + 1] * 16 + l16];
            uint2 x2 = hf8[(size_t)sorted[beg + e + 2] * 16 + l16];
            uint2 x3 = hf8[(size_t)sorted[beg + e + 3] * 16 + l16];
#pragma unroll
            for (int half = 0; half < 2; ++half) {
                unsigned w0 = half ? x0.y : x0.x, w1 = half ? x1.y : x1.x;
                unsigned w2 = half ? x2.y : x2.x, w3 = half ? x3.y : x3.x;
                floatx2 p;
                p = __builtin_amdgcn_cvt_pk_f32_fp8(w0, false); a0[half*4+0]+=p.x; a0[half*4+1]+=p.y;
                p = __builtin_amdgcn_cvt_pk_f32_fp8(w0, true);  a0[half*4+2]+=p.x; a0[half*4+3]+=p.y;
                p = __builtin_amdgcn_cvt_pk_f32_fp8(w1, false); a1[half*4+0]+=p.x; a1[half*4+1]+=p.y;
                p = __builtin_amdgcn_cvt_pk_f32_fp8(w1, true);  a1[half*4+2]+=p.x; a1[half*4+3]+=p.y;
                p = __builtin_amdgcn_cvt_pk_f32_fp8(w2, false); a2[half*4+0]+=p.x; a2[half*4+1]+=p.y;
                p = __builtin_amdgcn_cvt_pk_f32_fp8(w2, true);  a2[half*4+2]+=p.x; a2[half*4+3]+=p.y;
                p = __builtin_amdgcn_cvt_pk_f32_fp8(w3, false); a3[half*4+0]+=p.x; a3[half*4+1]+=p.y;
                p = __builtin_amdgcn_cvt_pk_f32_fp8(w3, true);  a3[half*4+2]+=p.x; a3[half*4+3]+=p.y;
            }
        }
        for (; e < n; ++e) {
            uint2 x = hf8[(size_t)sorted[beg + e] * 16 + l16];
#pragma unroll
            for (int half = 0; half < 2; ++half) {
                unsigned w = half ? x.y : x.x;
                floatx2 p;
                p = __builtin_amdgcn_cvt_pk_f32_fp8(w, false); a0[half*4+0]+=p.x; a0[half*4+1]+=p.y;
                p = __builtin_amdgcn_cvt_pk_f32_fp8(w, true);  a0[half*4+2]+=p.x; a0[half*4+3]+=p.y;
            }
        }
        float inv = (n > 0) ? 1.0f / (float)n : 0.0f;
        unsigned short m[8];
#pragma unroll
        for (int j = 0; j < 8; ++j)
            m[j] = f2bf((a0[j] + a1[j] + a2[j] + a3[j]) * inv);
        uint4 o;
        o.x = (unsigned)m[0] | ((unsigned)m[1] << 16);
        o.y = (unsigned)m[2] | ((unsigned)m[3] << 16);
        o.z = (unsigned)m[4] | ((unsigned)m[5] << 16);
        o.w = (unsigned)m[6] | ((unsigned)m[7] << 16);
        *(uint4*)&Xs[node][128 + l16 * 8] = o;
    }
    __syncthreads();

    // ---- Phase C: MFMA  out[64x128] = Xs(64x256) @ Wcat(256x128), 8 waves --
    const int wave  = t >> 6;            // 0..7
    const int lane  = t & 63;
    const int wl16  = lane & 15;
    const int kg4   = lane >> 4;         // 0..3
    const int wrow  = wave & 3;          // row-group 0..3
    const int chalf = wave >> 2;         // col half 0/1
    floatx4 acc[4];
#pragma unroll
    for (int c = 0; c < 4; ++c) acc[c] = (floatx4){0.f, 0.f, 0.f, 0.f};

    const int arow = wrow * 16 + wl16;   // 0..63
#pragma unroll
    for (int ks = 0; ks < 8; ++ks) {
        const short8 a = *(const short8*)&Xs[arow][ks * 32 + kg4 * 8];
#pragma unroll
        for (int c = 0; c < 4; ++c) {
            const int ct = chalf * 4 + c;
            const short8 b = *(const short8*)(Wp + (((ks * 4 + kg4) * 128) + ct * 16 + wl16) * 8);
            acc[c] = __builtin_amdgcn_mfma_f32_16x16x32_bf16(a, b, acc[c], 0, 0, 0);
        }
    }

    // C/D layout: col = lane&15, row = (lane>>4)*4 + reg
    const int rbase = bucket * BK + wrow * 16 + kg4 * 4;
#pragma unroll
    for (int r = 0; r < 4; ++r) {
        int row = rbase + r;
        if (row < NN) {
            float* o = out + (size_t)row * D + chalf * 64 + wl16;
#pragma unroll
            for (int c = 0; c < 4; ++c)
                o[c * 16] = acc[c][r];
        }
    }
}

extern "C" void kernel_launch(void* const* d_in, const int* in_sizes, int n_in,
                              void* d_out, int out_size, void* d_ws, size_t ws_size,
                              hipStream_t stream) {
    const float* h      = (const float*)d_in[0];
    const int*   src    = (const int*)d_in[1];
    const int*   dst    = (const int*)d_in[2];
    const float* Wself  = (const float*)d_in[3];
    const float* Wneigh = (const float*)d_in[4];
    float*       out    = (float*)d_out;

    // workspace layout (~45.4 MB)
    unsigned short* hb = (unsigned short*)d_ws;            // NN*D bf16 (25.6MB)
    uint2* hf8         = (uint2*)(hb + (size_t)NN * D);    // NN*D/8 uint2 (12.8MB)
    unsigned short* Wp = (unsigned short*)(hf8 + (size_t)NN * D / 8);  // 64KB
    unsigned* packed   = (unsigned*)(Wp + 256 * D);        // NE (6.4MB)
    int* bcnt          = (int*)(packed + NE);              // NB*PADI (200KB, padded)
    int* bbase         = bcnt + (size_t)NB * PADI;         // NB+1 (dense)
    uintptr_t bcur_a   = ((uintptr_t)(bbase + NB + 1) + 255) & ~(uintptr_t)255;
    int* bcursor       = (int*)bcur_a;                     // NB*PADI (200KB, padded)

    hipMemsetAsync(bcnt, 0, (size_t)NB * PADI * sizeof(int), stream);

    k_cvt_h    <<<dim3(NN * D / 8 / 256), 256, 0, stream>>>(h, dst, hb, hf8, bcnt);
    k_scan_cvtw<<<dim3(17), 256, 0, stream>>>(bcnt, bbase, bcursor, Wself, Wneigh, Wp);
    k_part     <<<dim3((NE + PB - 1) / PB), 256, 0, stream>>>(src, dst, bcursor, packed);
    k_agg_gemm <<<dim3(NB), 512, 0, stream>>>(hb, hf8, bbase, packed, Wp, out);
}

// Round 3
// 192.293 us; speedup vs baseline: 1.2928x; 1.2348x over previous
//
#include <hip/hip_runtime.h>

// SAGEConv — fp8-gather + fused aggregate/GEMM, fixed-capacity buckets.
// R9 post-mortem: k_agg 76->56.5us (chain depth + occ as predicted) but
// total only -11us -> atomic-padding theory for the invisible ~180us WRONG.
// Invisible time = serial load->atomic chains (k_cvt_h histogram 24-deep,
// k_part 32-deep w/ per-iter vmcnt drains; VGPR=40 proved no batching) +
// k_scan. R10: delete that work structurally:
//  (a) fixed-capacity buckets (base = b*2048; counts 1024+-32sigma) ->
//      no histogram, no scan kernel, 4 dispatches total;
//  (b) drop hb: Phase C self A-frag loads fp32 h direct (L3-resident) +
//      f2bf on the fly (bit-identical numerics); k_cvt = pure 64MB stream;
//      k_agg LDS 43->26.4KB -> 4 blocks/CU (wave cap);
//  (c) k_part: batch 32 dst+src loads into regs BEFORE atomics.

constexpr int NN = 100000;
constexpr int NE = 1600000;
constexpr int D  = 128;
constexpr int BK = 64;                      // nodes per bucket
constexpr int NB = (NN + BK - 1) / BK;      // 1563 buckets
constexpr int PB = 8192;                    // edges per partition block
constexpr int CAPB = 2048;                  // fixed bucket capacity (mean 1024, sigma 32)
constexpr int XSTN = 136;                   // Xs row stride (shorts): 272B -> 2-way bank alias (free)
constexpr int PADI = 32;                    // ints per bucket counter slot (128B line)
constexpr int CVT_BLOCKS = NN * D / 8 / 256;  // 6250 convert blocks

typedef __attribute__((ext_vector_type(8))) short short8;   // 8 bf16 (4 VGPR)
typedef __attribute__((ext_vector_type(4))) float floatx4;  // MFMA C/D
typedef __attribute__((ext_vector_type(2))) float floatx2;

static __device__ __forceinline__ unsigned short f2bf(float f) {
    unsigned u = __float_as_uint(f);
    unsigned r = ((u >> 16) & 1u) + 0x7fffu;
    return (unsigned short)((u + r) >> 16);
}

// ---------------------------------------------------------------------------
// Blocks 0..6249: h (fp32) -> hf8 (e4m3), pure streaming.
// Blocks 6250..6265: pack Wcat into B-fragment order (bf16), 2 kg per block.
// ---------------------------------------------------------------------------
__global__ __launch_bounds__(256) void k_cvt(
    const float* __restrict__ h, const float* __restrict__ Wself,
    const float* __restrict__ Wneigh, uint2* __restrict__ hf8,
    unsigned short* __restrict__ Wp)
{
    const int t = threadIdx.x;
    if (blockIdx.x < CVT_BLOCKS) {
        int i = blockIdx.x * 256 + t;                // 1.6M threads, exact
        const float4* h4 = (const float4*)h;
        float4 a = h4[(size_t)i * 2];
        float4 b = h4[(size_t)i * 2 + 1];
        unsigned q0 = __builtin_amdgcn_cvt_pk_fp8_f32(a.x, a.y, 0u, false);
        q0          = __builtin_amdgcn_cvt_pk_fp8_f32(a.z, a.w, q0, true);
        unsigned q1 = __builtin_amdgcn_cvt_pk_fp8_f32(b.x, b.y, 0u, false);
        q1          = __builtin_amdgcn_cvt_pk_fp8_f32(b.z, b.w, q1, true);
        hf8[i] = make_uint2(q0, q1);
    } else {
        int kg  = (blockIdx.x - CVT_BLOCKS) * 2 + (t >> 7);   // 0..31
        int col = t & 127;
        unsigned short v[8];
#pragma unroll
        for (int j = 0; j < 8; ++j) {
            int k = kg * 8 + j;
            const float* W = (k < 128) ? (Wself + (size_t)k * D)
                                       : (Wneigh + (size_t)(k - 128) * D);
            v[j] = f2bf(W[col]);
        }
        uint4 o;
        o.x = (unsigned)v[0] | ((unsigned)v[1] << 16);
        o.y = (unsigned)v[2] | ((unsigned)v[3] << 16);
        o.z = (unsigned)v[4] | ((unsigned)v[5] << 16);
        o.w = (unsigned)v[6] | ((unsigned)v[7] << 16);
        ((uint4*)Wp)[kg * 128 + col] = o;
    }
}

// ---------------------------------------------------------------------------
// Partition edges into fixed-capacity buckets: packed[b*CAPB + rank].
// All 32 dst+src loads batched into registers BEFORE any atomic (keeps 32
// loads in flight; no per-iteration vmcnt drain). One padded global reserve
// atomic per (block, bucket); bcursor ends up holding the bucket count.
// ---------------------------------------------------------------------------
__global__ __launch_bounds__(256) void k_part(
    const int* __restrict__ src, const int* __restrict__ dst,
    int* __restrict__ bcursor, unsigned* __restrict__ packed)
{
    __shared__ int lh[NB];
    const int t = threadIdx.x;
    const int e0 = blockIdx.x * PB;

    for (int i = t; i < NB; i += 256) lh[i] = 0;
    __syncthreads();

    int myd[32], msrc[32];
#pragma unroll
    for (int j = 0; j < 32; ++j) {
        int e = e0 + j * 256 + t;
        myd[j] = (e < NE) ? dst[e] : -1;
    }
#pragma unroll
    for (int j = 0; j < 32; ++j) {
        int e = e0 + j * 256 + t;
        msrc[j] = (e < NE) ? src[e] : 0;
    }
#pragma unroll
    for (int j = 0; j < 32; ++j)
        if (myd[j] >= 0) atomicAdd(&lh[myd[j] >> 6], 1);
    __syncthreads();
    for (int i = t; i < NB; i += 256) {
        int c = lh[i];
        if (c) lh[i] = atomicAdd(&bcursor[(size_t)i * PADI], c);
    }
    __syncthreads();
#pragma unroll
    for (int j = 0; j < 32; ++j) {
        if (myd[j] >= 0) {
            int b = myd[j] >> 6;
            int pos = atomicAdd(&lh[b], 1);            // within-bucket rank
            packed[(size_t)b * CAPB + pos] =
                (unsigned)msrc[j] | ((unsigned)(myd[j] & 63) << 17);
        }
    }
}

// ---------------------------------------------------------------------------
// Fused per-bucket kernel, 512 threads: counting-sort src (LDS), fp8 gather
// with 8-deep chains (32 groups x 2 nodes), mean bf16 into LDS Xs[64][136]
// (neighbor half only), then MFMA out[64x128] = [self|neigh] @ Wcat over
// 8 waves; self A-frags loaded fp32-direct from h (L3) + f2bf on the fly.
// LDS 26.4KB -> 4 blocks/CU (wave-cap).
// ---------------------------------------------------------------------------
__global__ __launch_bounds__(512, 8) void k_agg_gemm(
    const float* __restrict__ h, const uint2* __restrict__ hf8,
    const int* __restrict__ bcursor, const unsigned* __restrict__ packed,
    const unsigned short* __restrict__ Wp, float* __restrict__ out)
{
    __shared__ unsigned short Xs[BK][XSTN];    // 17.4 KiB neighbor tile (bf16)
    __shared__ unsigned sorted[CAPB];          // 8 KiB
    __shared__ int cnt[BK], offs[BK], cur[BK];

    const int t      = threadIdx.x;
    const int bucket = blockIdx.x;
    const size_t ebeg = (size_t)bucket * CAPB;
    const int ecnt   = min(bcursor[(size_t)bucket * PADI], CAPB);

    if (t < BK) cnt[t] = 0;
    __syncthreads();

    // ---- Phase A: counting sort of the bucket's edges into LDS ----
    unsigned pk[4];
#pragma unroll
    for (int i = 0; i < 4; ++i) {
        int idx = t + i * 512;
        pk[i] = (idx < ecnt) ? packed[ebeg + idx] : 0u;
    }
#pragma unroll
    for (int i = 0; i < 4; ++i) {
        int idx = t + i * 512;
        if (idx < ecnt) atomicAdd(&cnt[(pk[i] >> 17) & 63u], 1);
    }
    __syncthreads();
    if (t < BK) {                       // 64-wide shuffle scan (wave 0)
        int v = cnt[t];
        int sum = v;
#pragma unroll
        for (int off = 1; off < 64; off <<= 1) {
            int u = __shfl_up(sum, off, 64);
            if (t >= off) sum += u;
        }
        offs[t] = sum - v;
        cur[t]  = sum - v;
    }
    __syncthreads();
#pragma unroll
    for (int i = 0; i < 4; ++i) {
        int idx = t + i * 512;
        if (idx < ecnt) {
            int pos = atomicAdd(&cur[(pk[i] >> 17) & 63u], 1);
            sorted[pos] = pk[i] & 0x1FFFFu;
        }
    }
    __syncthreads();

    // ---- Phase B: fp8 gather, fp32 accumulate, mean -> Xs cols 0..127 ----
    // 32 groups of 16 lanes; each group: 2 nodes serially, 8 loads in flight.
    const int slot = t >> 4;            // 0..31
    const int l16  = t & 15;
#pragma unroll
    for (int ni = 0; ni < 2; ++ni) {
        int node = slot + ni * 32;      // 0..63
        const int beg = offs[node];
        const int n   = cnt[node];
        float a0[8] = {0,0,0,0,0,0,0,0};
        float a1[8] = {0,0,0,0,0,0,0,0};
        float a2[8] = {0,0,0,0,0,0,0,0};
        float a3[8] = {0,0,0,0,0,0,0,0};
        int e = 0;
        for (; e + 7 < n; e += 8) {
            uint2 x0 = hf8[(size_t)sorted[beg + e]     * 16 + l16];
            uint2 x1 = hf8[(size_t)sorted[beg + e + 1] * 16 + l16];
            uint2 x2 = hf8[(size_t)sorted[beg + e + 2] * 16 + l16];
            uint2 x3 = hf8[(size_t)sorted[beg + e + 3] * 16 + l16];
            uint2 x4 = hf8[(size_t)sorted[beg + e + 4] * 16 + l16];
            uint2 x5 = hf8[(size_t)sorted[beg + e + 5] * 16 + l16];
            uint2 x6 = hf8[(size_t)sorted[beg + e + 6] * 16 + l16];
            uint2 x7 = hf8[(size_t)sorted[beg + e + 7] * 16 + l16];
#pragma unroll
            for (int half = 0; half < 2; ++half) {
                unsigned w0 = half ? x0.y : x0.x, w1 = half ? x1.y : x1.x;
                unsigned w2 = half ? x2.y : x2.x, w3 = half ? x3.y : x3.x;
                unsigned w4 = half ? x4.y : x4.x, w5 = half ? x5.y : x5.x;
                unsigned w6 = half ? x6.y : x6.x, w7 = half ? x7.y : x7.x;
                floatx2 p;
                p = __builtin_amdgcn_cvt_pk_f32_fp8(w0, false); a0[half*4+0]+=p.x; a0[half*4+1]+=p.y;
                p = __builtin_amdgcn_cvt_pk_f32_fp8(w0, true);  a0[half*4+2]+=p.x; a0[half*4+3]+=p.y;
                p = __builtin_amdgcn_cvt_pk_f32_fp8(w1, false); a1[half*4+0]+=p.x; a1[half*4+1]+=p.y;
                p = __builtin_amdgcn_cvt_pk_f32_fp8(w1, true);  a1[half*4+2]+=p.x; a1[half*4+3]+=p.y;
                p = __builtin_amdgcn_cvt_pk_f32_fp8(w2, false); a2[half*4+0]+=p.x; a2[half*4+1]+=p.y;
                p = __builtin_amdgcn_cvt_pk_f32_fp8(w2, true);  a2[half*4+2]+=p.x; a2[half*4+3]+=p.y;
                p = __builtin_amdgcn_cvt_pk_f32_fp8(w3, false); a3[half*4+0]+=p.x; a3[half*4+1]+=p.y;
                p = __builtin_amdgcn_cvt_pk_f32_fp8(w3, true);  a3[half*4+2]+=p.x; a3[half*4+3]+=p.y;
                p = __builtin_amdgcn_cvt_pk_f32_fp8(w4, false); a0[half*4+0]+=p.x; a0[half*4+1]+=p.y;
                p = __builtin_amdgcn_cvt_pk_f32_fp8(w4, true);  a0[half*4+2]+=p.x; a0[half*4+3]+=p.y;
                p = __builtin_amdgcn_cvt_pk_f32_fp8(w5, false); a1[half*4+0]+=p.x; a1[half*4+1]+=p.y;
                p = __builtin_amdgcn_cvt_pk_f32_fp8(w5, true);  a1[half*4+2]+=p.x; a1[half*4+3]+=p.y;
                p = __builtin_amdgcn_cvt_pk_f32_fp8(w6, false); a2[half*4+0]+=p.x; a2[half*4+1]+=p.y;
                p = __builtin_amdgcn_cvt_pk_f32_fp8(w6, true);  a2[half*4+2]+=p.x; a2[half*4+3]+=p.y;
                p = __builtin_amdgcn_cvt_pk_f32_fp8(w7, false); a3[half*4+0]+=p.x; a3[half*4+1]+=p.y;
                p = __builtin_amdgcn_cvt_pk_f32_fp8(w7, true);  a3[half*4+2]+=p.x; a3[half*4+3]+=p.y;
            }
        }
        for (; e + 3 < n; e += 4) {
            uint2 x0 = hf8[(size_t)sorted[beg + e]     * 16 + l16];
            uint2 x1 = hf8[(size_t)sorted[beg + e + 1] * 16 + l16];
            uint2 x2 = hf8[(size_t)sorted[beg + e + 2] * 16 + l16];
            uint2 x3 = hf8[(size_t)sorted[beg + e + 3] * 16 + l16];
#pragma unroll
            for (int half = 0; half < 2; ++half) {
                unsigned w0 = half ? x0.y : x0.x, w1 = half ? x1.y : x1.x;
                unsigned w2 = half ? x2.y : x2.x, w3 = half ? x3.y : x3.x;
                floatx2 p;
                p = __builtin_amdgcn_cvt_pk_f32_fp8(w0, false); a0[half*4+0]+=p.x; a0[half*4+1]+=p.y;
                p = __builtin_amdgcn_cvt_pk_f32_fp8(w0, true);  a0[half*4+2]+=p.x; a0[half*4+3]+=p.y;
                p = __builtin_amdgcn_cvt_pk_f32_fp8(w1, false); a1[half*4+0]+=p.x; a1[half*4+1]+=p.y;
                p = __builtin_amdgcn_cvt_pk_f32_fp8(w1, true);  a1[half*4+2]+=p.x; a1[half*4+3]+=p.y;
                p = __builtin_amdgcn_cvt_pk_f32_fp8(w2, false); a2[half*4+0]+=p.x; a2[half*4+1]+=p.y;
                p = __builtin_amdgcn_cvt_pk_f32_fp8(w2, true);  a2[half*4+2]+=p.x; a2[half*4+3]+=p.y;
                p = __builtin_amdgcn_cvt_pk_f32_fp8(w3, false); a3[half*4+0]+=p.x; a3[half*4+1]+=p.y;
                p = __builtin_amdgcn_cvt_pk_f32_fp8(w3, true);  a3[half*4+2]+=p.x; a3[half*4+3]+=p.y;
            }
        }
        for (; e < n; ++e) {
            uint2 x = hf8[(size_t)sorted[beg + e] * 16 + l16];
#pragma unroll
            for (int half = 0; half < 2; ++half) {
                unsigned w = half ? x.y : x.x;
                floatx2 p;
                p = __builtin_amdgcn_cvt_pk_f32_fp8(w, false); a0[half*4+0]+=p.x; a0[half*4+1]+=p.y;
                p = __builtin_amdgcn_cvt_pk_f32_fp8(w, true);  a0[half*4+2]+=p.x; a0[half*4+3]+=p.y;
            }
        }
        float inv = (n > 0) ? 1.0f / (float)n : 0.0f;
        unsigned short m[8];
#pragma unroll
        for (int j = 0; j < 8; ++j)
            m[j] = f2bf((a0[j] + a1[j] + a2[j] + a3[j]) * inv);
        uint4 o;
        o.x = (unsigned)m[0] | ((unsigned)m[1] << 16);
        o.y = (unsigned)m[2] | ((unsigned)m[3] << 16);
        o.z = (unsigned)m[4] | ((unsigned)m[5] << 16);
        o.w = (unsigned)m[6] | ((unsigned)m[7] << 16);
        *(uint4*)&Xs[node][l16 * 8] = o;
    }
    __syncthreads();

    // ---- Phase C: MFMA  out[64x128] = [self | neigh] @ Wcat, 8 waves ----
    const int wave  = t >> 6;            // 0..7
    const int lane  = t & 63;
    const int wl16  = lane & 15;
    const int kg4   = lane >> 4;         // 0..3
    const int wrow  = wave & 3;          // row-group 0..3
    const int chalf = wave >> 2;         // col half 0/1
    floatx4 acc[4];
#pragma unroll
    for (int c = 0; c < 4; ++c) acc[c] = (floatx4){0.f, 0.f, 0.f, 0.f};

    const int arow = wrow * 16 + wl16;   // 0..63
    const int grow = min(bucket * BK + arow, NN - 1);
    const float* hrow = h + (size_t)grow * D + kg4 * 8;

    // self half: ks 0..3, A-frag fp32-direct from h + f2bf (== hb numerics)
#pragma unroll
    for (int ks = 0; ks < 4; ++ks) {
        float4 f0 = *(const float4*)(hrow + ks * 32);
        float4 f1 = *(const float4*)(hrow + ks * 32 + 4);
        uint4 q;
        q.x = (unsigned)f2bf(f0.x) | ((unsigned)f2bf(f0.y) << 16);
        q.y = (unsigned)f2bf(f0.z) | ((unsigned)f2bf(f0.w) << 16);
        q.z = (unsigned)f2bf(f1.x) | ((unsigned)f2bf(f1.y) << 16);
        q.w = (unsigned)f2bf(f1.z) | ((unsigned)f2bf(f1.w) << 16);
        const short8 a = *(const short8*)&q;
#pragma unroll
        for (int c = 0; c < 4; ++c) {
            const int ct = chalf * 4 + c;
            const short8 b = *(const short8*)(Wp + (((ks * 4 + kg4) * 128) + ct * 16 + wl16) * 8);
            acc[c] = __builtin_amdgcn_mfma_f32_16x16x32_bf16(a, b, acc[c], 0, 0, 0);
        }
    }
    // neighbor half: ks 4..7, A-frag from LDS Xs
#pragma unroll
    for (int ks = 4; ks < 8; ++ks) {
        const short8 a = *(const short8*)&Xs[arow][(ks - 4) * 32 + kg4 * 8];
#pragma unroll
        for (int c = 0; c < 4; ++c) {
            const int ct = chalf * 4 + c;
            const short8 b = *(const short8*)(Wp + (((ks * 4 + kg4) * 128) + ct * 16 + wl16) * 8);
            acc[c] = __builtin_amdgcn_mfma_f32_16x16x32_bf16(a, b, acc[c], 0, 0, 0);
        }
    }

    // C/D layout: col = lane&15, row = (lane>>4)*4 + reg
    const int rbase = bucket * BK + wrow * 16 + kg4 * 4;
#pragma unroll
    for (int r = 0; r < 4; ++r) {
        int row = rbase + r;
        if (row < NN) {
            float* o = out + (size_t)row * D + chalf * 64 + wl16;
#pragma unroll
            for (int c = 0; c < 4; ++c)
                o[c * 16] = acc[c][r];
        }
    }
}

extern "C" void kernel_launch(void* const* d_in, const int* in_sizes, int n_in,
                              void* d_out, int out_size, void* d_ws, size_t ws_size,
                              hipStream_t stream) {
    const float* h      = (const float*)d_in[0];
    const int*   src    = (const int*)d_in[1];
    const int*   dst    = (const int*)d_in[2];
    const float* Wself  = (const float*)d_in[3];
    const float* Wneigh = (const float*)d_in[4];
    float*       out    = (float*)d_out;

    // workspace layout (~26 MB)
    uint2* hf8         = (uint2*)d_ws;                         // NN*D/8 uint2 (12.8MB)
    unsigned short* Wp = (unsigned short*)(hf8 + (size_t)NN * D / 8);  // 64KB
    unsigned* packed   = (unsigned*)(Wp + 256 * D);            // NB*CAPB (12.8MB)
    uintptr_t bc_a     = ((uintptr_t)(packed + (size_t)NB * CAPB) + 255) & ~(uintptr_t)255;
    int* bcursor       = (int*)bc_a;                           // NB*PADI (200KB, padded)

    hipMemsetAsync(bcursor, 0, (size_t)NB * PADI * sizeof(int), stream);

    k_cvt      <<<dim3(CVT_BLOCKS + 16), 256, 0, stream>>>(h, Wself, Wneigh, hf8, Wp);
    k_part     <<<dim3((NE + PB - 1) / PB), 256, 0, stream>>>(src, dst, bcursor, packed);
    k_agg_gemm <<<dim3(NB), 512, 0, stream>>>(h, hf8, bcursor, packed, Wp, out);
}

// Round 4
// 183.378 us; speedup vs baseline: 1.3557x; 1.0486x over previous
//
#include <hip/hip_runtime.h>

// SAGEConv — fp8-gather + fused aggregate/GEMM, fixed-capacity buckets.
// R10 post-mortem: total 237->192 (structural deletes worked) but k_agg
// 56.5->65us: (a) Phase-C fp32 h loads serialized inside the MFMA loop
// (R9's Xs-preload overlapped them with the sort); (b) launch_bounds(512,8)
// VGPR cap ~64 forced Phase-B spills (reported VGPR=32 < 48 live floats).
// Ledger also doesn't close: non-k_agg ~127us vs ~30us modeled.
// R11: (1) k_agg: Xs-preload Phase C restored (fp32 h -> f2bf -> LDS in
//      Phase 0, pure-LDS MFMA), 4-deep/2-chain Phase B (no spill),
//      launch_bounds(512,6); LDS 42.5KB -> 3 blocks/CU.
//      (2) ONE k_prep dispatch = part(196 blocks, first) + Wpack(16) +
//      cvt(6250): prep wall = max not sum; exposes launch overhead if any.

constexpr int NN = 100000;
constexpr int NE = 1600000;
constexpr int D  = 128;
constexpr int BK = 64;                      // nodes per bucket
constexpr int NB = (NN + BK - 1) / BK;      // 1563 buckets
constexpr int PB = 8192;                    // edges per partition block
constexpr int CAPB = 2048;                  // fixed bucket capacity (mean 1024, sigma 32)
constexpr int XST = 264;                    // Xs row stride (shorts): 528B
constexpr int PADI = 32;                    // ints per bucket counter slot (128B line)
constexpr int PART_BLOCKS = (NE + PB - 1) / PB;   // 196
constexpr int WPK_BLOCKS  = 16;
constexpr int CVT_BLOCKS  = NN * D / 8 / 256;     // 6250

typedef __attribute__((ext_vector_type(8))) short short8;   // 8 bf16 (4 VGPR)
typedef __attribute__((ext_vector_type(4))) float floatx4;  // MFMA C/D
typedef __attribute__((ext_vector_type(2))) float floatx2;

static __device__ __forceinline__ unsigned short f2bf(float f) {
    unsigned u = __float_as_uint(f);
    unsigned r = ((u >> 16) & 1u) + 0x7fffu;
    return (unsigned short)((u + r) >> 16);
}

// ---------------------------------------------------------------------------
// Fused prep: blocks [0,196) partition edges; [196,212) pack Wcat;
// [212,6462) h fp32 -> fp8. Part blocks first so the long pole starts
// immediately while cvt blocks fill the remaining CUs.
// ---------------------------------------------------------------------------
__global__ __launch_bounds__(256) void k_prep(
    const float* __restrict__ h, const float* __restrict__ Wself,
    const float* __restrict__ Wneigh, const int* __restrict__ src,
    const int* __restrict__ dst, uint2* __restrict__ hf8,
    unsigned short* __restrict__ Wp, int* __restrict__ bcursor,
    unsigned* __restrict__ packed)
{
    const int t = threadIdx.x;
    if (blockIdx.x < PART_BLOCKS) {
        // ---- edge partition into fixed-capacity buckets ----
        __shared__ int lh[NB];
        const int e0 = blockIdx.x * PB;
        for (int i = t; i < NB; i += 256) lh[i] = 0;
        __syncthreads();

        int myd[32], msrc[32];
#pragma unroll
        for (int j = 0; j < 32; ++j) {
            int e = e0 + j * 256 + t;
            myd[j] = (e < NE) ? dst[e] : -1;
        }
#pragma unroll
        for (int j = 0; j < 32; ++j) {
            int e = e0 + j * 256 + t;
            msrc[j] = (e < NE) ? src[e] : 0;
        }
#pragma unroll
        for (int j = 0; j < 32; ++j)
            if (myd[j] >= 0) atomicAdd(&lh[myd[j] >> 6], 1);
        __syncthreads();
        for (int i = t; i < NB; i += 256) {
            int c = lh[i];
            if (c) lh[i] = atomicAdd(&bcursor[(size_t)i * PADI], c);
        }
        __syncthreads();
#pragma unroll
        for (int j = 0; j < 32; ++j) {
            if (myd[j] >= 0) {
                int b = myd[j] >> 6;
                int pos = atomicAdd(&lh[b], 1);        // within-bucket rank
                packed[(size_t)b * CAPB + pos] =
                    (unsigned)msrc[j] | ((unsigned)(myd[j] & 63) << 17);
            }
        }
    } else if (blockIdx.x < PART_BLOCKS + WPK_BLOCKS) {
        // ---- pack Wcat into B-fragment order (bf16) ----
        int kg  = (blockIdx.x - PART_BLOCKS) * 2 + (t >> 7);   // 0..31
        int col = t & 127;
        unsigned short v[8];
#pragma unroll
        for (int j = 0; j < 8; ++j) {
            int k = kg * 8 + j;
            const float* W = (k < 128) ? (Wself + (size_t)k * D)
                                       : (Wneigh + (size_t)(k - 128) * D);
            v[j] = f2bf(W[col]);
        }
        uint4 o;
        o.x = (unsigned)v[0] | ((unsigned)v[1] << 16);
        o.y = (unsigned)v[2] | ((unsigned)v[3] << 16);
        o.z = (unsigned)v[4] | ((unsigned)v[5] << 16);
        o.w = (unsigned)v[6] | ((unsigned)v[7] << 16);
        ((uint4*)Wp)[kg * 128 + col] = o;
    } else {
        // ---- h (fp32) -> hf8 (e4m3), pure streaming ----
        int i = (blockIdx.x - PART_BLOCKS - WPK_BLOCKS) * 256 + t;
        const float4* h4 = (const float4*)h;
        float4 a = h4[(size_t)i * 2];
        float4 b = h4[(size_t)i * 2 + 1];
        unsigned q0 = __builtin_amdgcn_cvt_pk_fp8_f32(a.x, a.y, 0u, false);
        q0          = __builtin_amdgcn_cvt_pk_fp8_f32(a.z, a.w, q0, true);
        unsigned q1 = __builtin_amdgcn_cvt_pk_fp8_f32(b.x, b.y, 0u, false);
        q1          = __builtin_amdgcn_cvt_pk_fp8_f32(b.z, b.w, q1, true);
        hf8[i] = make_uint2(q0, q1);
    }
}

// ---------------------------------------------------------------------------
// Fused per-bucket kernel, 512 threads:
//   Phase 0: self rows fp32 -> bf16 -> Xs cols 0..127 (overlaps Phase A).
//   Phase A: counting-sort the bucket's edges into LDS.
//   Phase B: fp8 gather, 4-deep loads, 2 fp32 acc chains (no spill),
//            mean bf16 -> Xs cols 128..255.
//   Phase C: pure-LDS MFMA out[64x128] = Xs(64x256) @ Wcat, 8 waves.
// LDS 42.5KB -> 3 blocks/CU; launch_bounds(512,6) caps VGPR ~85.
// ---------------------------------------------------------------------------
__global__ __launch_bounds__(512, 6) void k_agg_gemm(
    const float* __restrict__ h, const uint2* __restrict__ hf8,
    const int* __restrict__ bcursor, const unsigned* __restrict__ packed,
    const unsigned short* __restrict__ Wp, float* __restrict__ out)
{
    __shared__ unsigned short Xs[BK][XST];     // 33.7 KiB A-tile (bf16)
    __shared__ unsigned sorted[CAPB];          // 8 KiB
    __shared__ int cnt[BK], offs[BK], cur[BK];

    const int t      = threadIdx.x;
    const int bucket = blockIdx.x;
    const size_t ebeg = (size_t)bucket * CAPB;
    const int ecnt   = min(bcursor[(size_t)bucket * PADI], CAPB);

    if (t < BK) cnt[t] = 0;

    // ---- Phase 0: self rows fp32 -> bf16 into Xs cols 0..127 ----
    {
        int row = t >> 3, seg = t & 7;          // 64 rows x 8 segs of 16 floats
        int grow = min(bucket * BK + row, NN - 1);
        const float4* hp = (const float4*)(h + (size_t)grow * D + seg * 16);
        float4 f0 = hp[0], f1 = hp[1], f2 = hp[2], f3 = hp[3];
        uint4 q0, q1;
        q0.x = (unsigned)f2bf(f0.x) | ((unsigned)f2bf(f0.y) << 16);
        q0.y = (unsigned)f2bf(f0.z) | ((unsigned)f2bf(f0.w) << 16);
        q0.z = (unsigned)f2bf(f1.x) | ((unsigned)f2bf(f1.y) << 16);
        q0.w = (unsigned)f2bf(f1.z) | ((unsigned)f2bf(f1.w) << 16);
        q1.x = (unsigned)f2bf(f2.x) | ((unsigned)f2bf(f2.y) << 16);
        q1.y = (unsigned)f2bf(f2.z) | ((unsigned)f2bf(f2.w) << 16);
        q1.z = (unsigned)f2bf(f3.x) | ((unsigned)f2bf(f3.y) << 16);
        q1.w = (unsigned)f2bf(f3.z) | ((unsigned)f2bf(f3.w) << 16);
        *(uint4*)&Xs[row][seg * 16]     = q0;
        *(uint4*)&Xs[row][seg * 16 + 8] = q1;
    }
    __syncthreads();

    // ---- Phase A: counting sort of the bucket's edges into LDS ----
    unsigned pk[4];
#pragma unroll
    for (int i = 0; i < 4; ++i) {
        int idx = t + i * 512;
        pk[i] = (idx < ecnt) ? packed[ebeg + idx] : 0u;
    }
#pragma unroll
    for (int i = 0; i < 4; ++i) {
        int idx = t + i * 512;
        if (idx < ecnt) atomicAdd(&cnt[(pk[i] >> 17) & 63u], 1);
    }
    __syncthreads();
    if (t < BK) {                       // 64-wide shuffle scan (wave 0)
        int v = cnt[t];
        int sum = v;
#pragma unroll
        for (int off = 1; off < 64; off <<= 1) {
            int u = __shfl_up(sum, off, 64);
            if (t >= off) sum += u;
        }
        offs[t] = sum - v;
        cur[t]  = sum - v;
    }
    __syncthreads();
#pragma unroll
    for (int i = 0; i < 4; ++i) {
        int idx = t + i * 512;
        if (idx < ecnt) {
            int pos = atomicAdd(&cur[(pk[i] >> 17) & 63u], 1);
            sorted[pos] = pk[i] & 0x1FFFFu;
        }
    }
    __syncthreads();

    // ---- Phase B: fp8 gather, fp32 accumulate, mean -> Xs cols 128..255 ---
    // 32 groups of 16 lanes; 2 nodes/group serially; 4 loads in flight,
    // 2 accumulator chains (24 live floats -> no spill at VGPR cap ~85).
    const int slot = t >> 4;            // 0..31
    const int l16  = t & 15;
#pragma unroll
    for (int ni = 0; ni < 2; ++ni) {
        int node = slot + ni * 32;      // 0..63
        const int beg = offs[node];
        const int n   = cnt[node];
        float a0[8] = {0,0,0,0,0,0,0,0};
        float a1[8] = {0,0,0,0,0,0,0,0};
        int e = 0;
        for (; e + 3 < n; e += 4) {
            uint2 x0 = hf8[(size_t)sorted[beg + e]     * 16 + l16];
            uint2 x1 = hf8[(size_t)sorted[beg + e + 1] * 16 + l16];
            uint2 x2 = hf8[(size_t)sorted[beg + e + 2] * 16 + l16];
            uint2 x3 = hf8[(size_t)sorted[beg + e + 3] * 16 + l16];
#pragma unroll
            for (int half = 0; half < 2; ++half) {
                unsigned w0 = half ? x0.y : x0.x, w1 = half ? x1.y : x1.x;
                unsigned w2 = half ? x2.y : x2.x, w3 = half ? x3.y : x3.x;
                floatx2 p;
                p = __builtin_amdgcn_cvt_pk_f32_fp8(w0, false); a0[half*4+0]+=p.x; a0[half*4+1]+=p.y;
                p = __builtin_amdgcn_cvt_pk_f32_fp8(w0, true);  a0[half*4+2]+=p.x; a0[half*4+3]+=p.y;
                p = __builtin_amdgcn_cvt_pk_f32_fp8(w1, false); a1[half*4+0]+=p.x; a1[half*4+1]+=p.y;
                p = __builtin_amdgcn_cvt_pk_f32_fp8(w1, true);  a1[half*4+2]+=p.x; a1[half*4+3]+=p.y;
                p = __builtin_amdgcn_cvt_pk_f32_fp8(w2, false); a0[half*4+0]+=p.x; a0[half*4+1]+=p.y;
                p = __builtin_amdgcn_cvt_pk_f32_fp8(w2, true);  a0[half*4+2]+=p.x; a0[half*4+3]+=p.y;
                p = __builtin_amdgcn_cvt_pk_f32_fp8(w3, false); a1[half*4+0]+=p.x; a1[half*4+1]+=p.y;
                p = __builtin_amdgcn_cvt_pk_f32_fp8(w3, true);  a1[half*4+2]+=p.x; a1[half*4+3]+=p.y;
            }
        }
        for (; e < n; ++e) {
            uint2 x = hf8[(size_t)sorted[beg + e] * 16 + l16];
#pragma unroll
            for (int half = 0; half < 2; ++half) {
                unsigned w = half ? x.y : x.x;
                floatx2 p;
                p = __builtin_amdgcn_cvt_pk_f32_fp8(w, false); a0[half*4+0]+=p.x; a0[half*4+1]+=p.y;
                p = __builtin_amdgcn_cvt_pk_f32_fp8(w, true);  a0[half*4+2]+=p.x; a0[half*4+3]+=p.y;
            }
        }
        float inv = (n > 0) ? 1.0f / (float)n : 0.0f;
        unsigned short m[8];
#pragma unroll
        for (int j = 0; j < 8; ++j)
            m[j] = f2bf((a0[j] + a1[j]) * inv);
        uint4 o;
        o.x = (unsigned)m[0] | ((unsigned)m[1] << 16);
        o.y = (unsigned)m[2] | ((unsigned)m[3] << 16);
        o.z = (unsigned)m[4] | ((unsigned)m[5] << 16);
        o.w = (unsigned)m[6] | ((unsigned)m[7] << 16);
        *(uint4*)&Xs[node][128 + l16 * 8] = o;
    }
    __syncthreads();

    // ---- Phase C: MFMA  out[64x128] = Xs(64x256) @ Wcat(256x128), 8 waves -
    const int wave  = t >> 6;            // 0..7
    const int lane  = t & 63;
    const int wl16  = lane & 15;
    const int kg4   = lane >> 4;         // 0..3
    const int wrow  = wave & 3;          // row-group 0..3
    const int chalf = wave >> 2;         // col half 0/1
    floatx4 acc[4];
#pragma unroll
    for (int c = 0; c < 4; ++c) acc[c] = (floatx4){0.f, 0.f, 0.f, 0.f};

    const int arow = wrow * 16 + wl16;   // 0..63
#pragma unroll
    for (int ks = 0; ks < 8; ++ks) {
        const short8 a = *(const short8*)&Xs[arow][ks * 32 + kg4 * 8];
#pragma unroll
        for (int c = 0; c < 4; ++c) {
            const int ct = chalf * 4 + c;
            const short8 b = *(const short8*)(Wp + (((ks * 4 + kg4) * 128) + ct * 16 + wl16) * 8);
            acc[c] = __builtin_amdgcn_mfma_f32_16x16x32_bf16(a, b, acc[c], 0, 0, 0);
        }
    }

    // C/D layout: col = lane&15, row = (lane>>4)*4 + reg
    const int rbase = bucket * BK + wrow * 16 + kg4 * 4;
#pragma unroll
    for (int r = 0; r < 4; ++r) {
        int row = rbase + r;
        if (row < NN) {
            float* o = out + (size_t)row * D + chalf * 64 + wl16;
#pragma unroll
            for (int c = 0; c < 4; ++c)
                o[c * 16] = acc[c][r];
        }
    }
}

extern "C" void kernel_launch(void* const* d_in, const int* in_sizes, int n_in,
                              void* d_out, int out_size, void* d_ws, size_t ws_size,
                              hipStream_t stream) {
    const float* h      = (const float*)d_in[0];
    const int*   src    = (const int*)d_in[1];
    const int*   dst    = (const int*)d_in[2];
    const float* Wself  = (const float*)d_in[3];
    const float* Wneigh = (const float*)d_in[4];
    float*       out    = (float*)d_out;

    // workspace layout (~26 MB)
    uint2* hf8         = (uint2*)d_ws;                         // NN*D/8 uint2 (12.8MB)
    unsigned short* Wp = (unsigned short*)(hf8 + (size_t)NN * D / 8);  // 64KB
    unsigned* packed   = (unsigned*)(Wp + 256 * D);            // NB*CAPB (12.8MB)
    uintptr_t bc_a     = ((uintptr_t)(packed + (size_t)NB * CAPB) + 255) & ~(uintptr_t)255;
    int* bcursor       = (int*)bc_a;                           // NB*PADI (200KB, padded)

    hipMemsetAsync(bcursor, 0, (size_t)NB * PADI * sizeof(int), stream);

    k_prep     <<<dim3(PART_BLOCKS + WPK_BLOCKS + CVT_BLOCKS), 256, 0, stream>>>(
                   h, Wself, Wneigh, src, dst, hf8, Wp, bcursor, packed);
    k_agg_gemm <<<dim3(NB), 512, 0, stream>>>(h, hf8, bcursor, packed, Wp, out);
}